// Round 4
// baseline (165.515 us; speedup 1.0000x reference)
//
#include <hip/hip_runtime.h>

// SRHT via MFMA, transposed chain: FWHT1024 = H32 (x) H32 on a 32x32 matrix.
// Start A = mat(x*rad0) ROW-major (contiguous 8-float per-lane loads). Each
// pair of products then yields h^T: C2=h1^T, C4=h2^T, C6=h3^T. rad1/rad2 are
// applied in transposed layout rad[32q+rr] = 4 contiguous float4 per lane.
// VMEM/thread: 24 vector instrs (was 64 scalar + 8 vector).
// h-store uses XOR swizzle (rr ^ (q&30)): conflict-free, b64-pair aligned;
// gather unswizzles with phys = p ^ ((p>>5)&30).

typedef float f32x16 __attribute__((ext_vector_type(16)));
typedef __fp16 f16x8 __attribute__((ext_vector_type(8)));
typedef unsigned int uintv2 __attribute__((ext_vector_type(2)));

union H8U4 { f16x8 h; unsigned int u[4]; };

__device__ __forceinline__ unsigned int pkrtz(float a, float b) {
  auto p = __builtin_amdgcn_cvt_pkrtz(a, b);   // lo = f16(a), hi = f16(b)
  return __builtin_bit_cast(unsigned int, p);
}

__device__ __forceinline__ f32x16 prod(const f16x8& A0, const f16x8& A1,
                                       const f16x8& B0, const f16x8& B1) {
  f32x16 z = {0.f,0.f,0.f,0.f, 0.f,0.f,0.f,0.f, 0.f,0.f,0.f,0.f, 0.f,0.f,0.f,0.f};
  z = __builtin_amdgcn_mfma_f32_32x32x16_f16(A0, B0, z, 0, 0, 0);
  z = __builtin_amdgcn_mfma_f32_32x32x16_f16(A1, B1, z, 0, 0, 0);
  return z;
}

// C (f32x16, col=lane&31, row=(j&3)+8*(j>>2)+4*hi) -> A fragments of C^T.
__device__ __forceinline__ void convA(const f32x16& c, f16x8& A0, f16x8& A1) {
  unsigned int W[8];
#pragma unroll
  for (int m = 0; m < 8; m++) W[m] = pkrtz(c[2 * m], c[2 * m + 1]);
  H8U4 a0, a1;
  uintv2 r;
  r = __builtin_amdgcn_permlane32_swap(W[0], W[2], false, false); a0.u[0] = r[0]; a0.u[2] = r[1];
  r = __builtin_amdgcn_permlane32_swap(W[1], W[3], false, false); a0.u[1] = r[0]; a0.u[3] = r[1];
  r = __builtin_amdgcn_permlane32_swap(W[4], W[6], false, false); a1.u[0] = r[0]; a1.u[2] = r[1];
  r = __builtin_amdgcn_permlane32_swap(W[5], W[7], false, false); a1.u[1] = r[0]; a1.u[3] = r[1];
  A0 = a0.h; A1 = a1.h;
}

__global__ __launch_bounds__(256) void srht_kernel(
    const float* __restrict__ x, const float* __restrict__ rad,
    const int* __restrict__ perm, float* __restrict__ out) {
  __shared__ __align__(16) float lds[4096];
  const int row  = blockIdx.x;
  const int tid  = threadIdx.x;
  const int w    = tid >> 6;        // FWHT block
  const int lane = tid & 63;
  const int q    = lane & 31;       // matrix column owned by this lane
  const int hi   = lane >> 5;

  // ---- H32 B-fragments via XOR chain. u[m] packs k-pair (16t+8hi+2m, +1),
  //      sign(H[k][q]) = popc(k&q)&1. Base k=8hi; +1 toggles by q bit0 (hi
  //      half only), +2 by q bit1, +4 by q bit2, +16 by q bit4. ----
  f16x8 B0, B1;
  {
    unsigned sb = (hi & (q >> 3)) & 1u;
    unsigned u0 = 0x3C003C00u ^ (sb * 0x80008000u) ^ ((unsigned)(q & 1) << 31);
    unsigned m2  = (q & 2)  ? 0x80008000u : 0u;
    unsigned m4  = (q & 4)  ? 0x80008000u : 0u;
    unsigned m16 = (q & 16) ? 0x80008000u : 0u;
    H8U4 b0, b1;
    b0.u[0] = u0;      b0.u[1] = u0 ^ m2;
    b0.u[2] = u0 ^ m4; b0.u[3] = u0 ^ m2 ^ m4;
#pragma unroll
    for (int m = 0; m < 4; m++) b1.u[m] = b0.u[m] ^ m16;
    B0 = b0.h; B1 = b1.h;
  }

  // ---- first A = mat(x*rad0) row-major: lane q holds row q,
  //      k = 16t + 8hi + 0..7  ->  x[32q + 16t + 8hi + 0..7], contiguous ----
  f16x8 A0, A1;
  {
    const float4* xq = (const float4*)(x + (size_t)row * 1024) + (q << 3) + (hi << 1);
    const float4* rq = (const float4*)rad + (w << 8) + (q << 3) + (hi << 1);
    H8U4 a0, a1;
#pragma unroll
    for (int t = 0; t < 2; t++) {
      float4 xa = xq[4 * t], xb = xq[4 * t + 1];
      float4 ra = rq[4 * t], rb = rq[4 * t + 1];
      unsigned w0 = pkrtz(xa.x * ra.x, xa.y * ra.y);
      unsigned w1 = pkrtz(xa.z * ra.z, xa.w * ra.w);
      unsigned w2 = pkrtz(xb.x * rb.x, xb.y * rb.y);
      unsigned w3 = pkrtz(xb.z * rb.z, xb.w * rb.w);
      if (t == 0) { a0.u[0] = w0; a0.u[1] = w1; a0.u[2] = w2; a0.u[3] = w3; }
      else        { a1.u[0] = w0; a1.u[1] = w1; a1.u[2] = w2; a1.u[3] = w3; }
    }
    A0 = a0.h; A1 = a1.h;
  }

  f32x16 c;
  c = prod(A0, A1, B0, B1);                    // C1 = M0 * H
  convA(c, A0, A1);
  c = prod(A0, A1, B0, B1);                    // C2 = h1^T : c[j] = h1[32q+rr]

  // ---- (1/32)*rad1, transposed layout: rr = 8s + 4hi + jj ----
  {
    const float4* r1q = (const float4*)(rad + 4096 + (w << 10) + (q << 5) + (hi << 2));
#pragma unroll
    for (int s = 0; s < 4; s++) {
      float4 rv = r1q[2 * s];
      c[4 * s + 0] *= 0.03125f * rv.x;
      c[4 * s + 1] *= 0.03125f * rv.y;
      c[4 * s + 2] *= 0.03125f * rv.z;
      c[4 * s + 3] *= 0.03125f * rv.w;
    }
  }
  convA(c, A0, A1);
  c = prod(A0, A1, B0, B1);                    // C3
  convA(c, A0, A1);
  c = prod(A0, A1, B0, B1);                    // C4 = h2^T

  // ---- (1/32)*rad2 ----
  {
    const float4* r2q = (const float4*)(rad + 8192 + (w << 10) + (q << 5) + (hi << 2));
#pragma unroll
    for (int s = 0; s < 4; s++) {
      float4 rv = r2q[2 * s];
      c[4 * s + 0] *= 0.03125f * rv.x;
      c[4 * s + 1] *= 0.03125f * rv.y;
      c[4 * s + 2] *= 0.03125f * rv.z;
      c[4 * s + 3] *= 0.03125f * rv.w;
    }
  }
  convA(c, A0, A1);
  c = prod(A0, A1, B0, B1);                    // C5
  convA(c, A0, A1);
  c = prod(A0, A1, B0, B1);                    // C6 = h3^T : c[j] = h3[32q+rr]

  // ---- h -> LDS, XOR-swizzled: word = (q<<5) | (rr ^ (q&30)).
  //      Conflict-free (2-way) and keeps b64 pair alignment. ----
  {
    const int base = (w << 10) + (q << 5);
    const int qm = q & 30;
#pragma unroll
    for (int s = 0; s < 4; s++) {
      int rr0 = 8 * s + (hi << 2);
      float2 p01; p01.x = c[4 * s + 0]; p01.y = c[4 * s + 1];
      float2 p23; p23.x = c[4 * s + 2]; p23.y = c[4 * s + 3];
      *(float2*)(lds + base + ((rr0 + 0) ^ qm)) = p01;
      *(float2*)(lds + base + ((rr0 + 2) ^ qm)) = p23;
    }
  }
  __syncthreads();

  // ---- permutation gather: j = g*1024 + tid*4, coalesced perm loads and
  //      1KB/wave float4 stores; unswizzle phys = p ^ ((p>>5)&30) ----
  {
    float* orow = out + (size_t)row * 4096;
#pragma unroll
    for (int g = 0; g < 4; g++) {
      int j = (g << 10) + (tid << 2);
      int4 pi = *(const int4*)(perm + j);
      float4 o;
      o.x = lds[pi.x ^ ((pi.x >> 5) & 30)];
      o.y = lds[pi.y ^ ((pi.y >> 5) & 30)];
      o.z = lds[pi.z ^ ((pi.z >> 5) & 30)];
      o.w = lds[pi.w ^ ((pi.w >> 5) & 30)];
      *(float4*)(orow + j) = o;
    }
  }
}

extern "C" void kernel_launch(void* const* d_in, const int* in_sizes, int n_in,
                              void* d_out, int out_size, void* d_ws, size_t ws_size,
                              hipStream_t stream) {
  (void)n_in; (void)d_ws; (void)ws_size; (void)out_size;
  const float* x    = (const float*)d_in[0];
  const float* rad  = (const float*)d_in[1];
  const int*   perm = (const int*)d_in[2];
  float*       out  = (float*)d_out;
  const int rows = in_sizes[0] / 1024;  // 16384
  srht_kernel<<<rows, 256, 0, stream>>>(x, rad, perm, out);
}

// Round 5
// 76.698 us; speedup vs baseline: 2.1580x; 2.1580x over previous
//
#include <hip/hip_runtime.h>

// SRHT via MFMA, row-batched: FWHT1024 = H32 (x) H32 on a 32x32 matrix view.
// Chain of 6 mfma_f32_32x32x16_f16 products per row (verified R2/R3 structure):
//   P1(B),P2(B)=fwht1; P3(Bs),P4(B)=fwht2*(1/32); P5(Bs),P6(B)=fwht3*(1/32).
// R5: 8 rows/block. Loop-invariants in registers: B/Bs fragments, rad0/1/2 as
// packed f16 SIGN MASKS (xor after cvt_pkrtz == exact +-1 multiply), perm
// indices. Per-row VMEM = 16 wave-COALESCED x scalars (lane q reads x[32k+q]),
// prefetched one row ahead. Double-buffered h in LDS -> ONE barrier per row.

typedef float f32x16 __attribute__((ext_vector_type(16)));
typedef __fp16 f16x8 __attribute__((ext_vector_type(8)));
typedef unsigned int uintv2 __attribute__((ext_vector_type(2)));

union H8U4 { f16x8 h; unsigned int u[4]; };

#define RPB 8  // rows per block

__device__ __forceinline__ unsigned int pkrtz(float a, float b) {
  auto p = __builtin_amdgcn_cvt_pkrtz(a, b);   // lo = f16(a), hi = f16(b)
  return __builtin_bit_cast(unsigned int, p);
}

__device__ __forceinline__ f32x16 prod(const f16x8& A0, const f16x8& A1,
                                       const f16x8& B0, const f16x8& B1) {
  f32x16 z = {0.f,0.f,0.f,0.f, 0.f,0.f,0.f,0.f, 0.f,0.f,0.f,0.f, 0.f,0.f,0.f,0.f};
  z = __builtin_amdgcn_mfma_f32_32x32x16_f16(A0, B0, z, 0, 0, 0);
  z = __builtin_amdgcn_mfma_f32_32x32x16_f16(A1, B1, z, 0, 0, 0);
  return z;
}

// C (col=lane&31, row=(j&3)+8*(j>>2)+4*hi) -> A fragments of C^T.
// Optional sign-mask XOR (rad multiply) applied to packed words PRE-swap.
template <bool RADM>
__device__ __forceinline__ void convA(const f32x16& c, const unsigned (&msk)[8],
                                      f16x8& A0, f16x8& A1) {
  unsigned W[8];
#pragma unroll
  for (int m = 0; m < 8; m++) {
    unsigned wd = pkrtz(c[2 * m], c[2 * m + 1]);
    if (RADM) wd ^= msk[m];
    W[m] = wd;
  }
  H8U4 a0, a1; uintv2 r;
  r = __builtin_amdgcn_permlane32_swap(W[0], W[2], false, false); a0.u[0]=r[0]; a0.u[2]=r[1];
  r = __builtin_amdgcn_permlane32_swap(W[1], W[3], false, false); a0.u[1]=r[0]; a0.u[3]=r[1];
  r = __builtin_amdgcn_permlane32_swap(W[4], W[6], false, false); a1.u[0]=r[0]; a1.u[2]=r[1];
  r = __builtin_amdgcn_permlane32_swap(W[5], W[7], false, false); a1.u[1]=r[0]; a1.u[3]=r[1];
  A0 = a0.h; A1 = a1.h;
}

__global__ __launch_bounds__(256) void srht_kernel(
    const float* __restrict__ x, const float* __restrict__ rad,
    const int* __restrict__ perm, float* __restrict__ out) {
  __shared__ __align__(16) float lds[8192];   // 2 x 4096 (double-buffered h)
  const int tid  = threadIdx.x;
  const int w    = tid >> 6;        // FWHT block
  const int lane = tid & 63;
  const int q    = lane & 31;
  const int hi   = lane >> 5;
  const size_t row0 = (size_t)blockIdx.x * RPB;

  // ---- B / Bs fragments via XOR chain (sign(H[k][q]) = popc(k&q)&1) ----
  f16x8 B0, B1, Bs0, Bs1;
  {
    unsigned sb  = (hi & (q >> 3)) & 1u;
    unsigned sx  = (sb * 0x80008000u) ^ ((unsigned)(q & 1) << 31);
    unsigned m2  = (q & 2)  ? 0x80008000u : 0u;
    unsigned m4  = (q & 4)  ? 0x80008000u : 0u;
    unsigned m16 = (q & 16) ? 0x80008000u : 0u;
    H8U4 b0, b1, s0, s1;
    unsigned u0 = 0x3C003C00u ^ sx;   // +-1.0
    unsigned v0 = 0x28002800u ^ sx;   // +-2^-5
    b0.u[0]=u0; b0.u[1]=u0^m2; b0.u[2]=u0^m4; b0.u[3]=u0^m2^m4;
    s0.u[0]=v0; s0.u[1]=v0^m2; s0.u[2]=v0^m4; s0.u[3]=v0^m2^m4;
#pragma unroll
    for (int m = 0; m < 4; m++) { b1.u[m]=b0.u[m]^m16; s1.u[m]=s0.u[m]^m16; }
    B0=b0.h; B1=b1.h; Bs0=s0.h; Bs1=s1.h;
  }

  // ---- rad sign masks (loaded once; wave-coalesced scalar reads) ----
  unsigned r0m[8], r1m[8], r2m[8];
  {
    const float* r0 = rad + (w << 10) + q;
    const float* r1 = rad + ((4 + w) << 10) + q;
    const float* r2 = rad + ((8 + w) << 10) + q;
#pragma unroll
    for (int t = 0; t < 2; t++)
#pragma unroll
      for (int m = 0; m < 4; m++) {
        int k0 = 16*t + 8*hi + 2*m;   // A-word (t,m) packs rows k0, k0+1
        unsigned sa = __float_as_uint(r0[k0 << 5]) >> 31;
        unsigned sc = __float_as_uint(r0[(k0 + 1) << 5]) >> 31;
        r0m[4*t + m] = (sa << 15) | (sc << 31);
      }
#pragma unroll
    for (int m = 0; m < 8; m++) {     // convA word m packs c[2m], c[2m+1]
      int j0 = 2*m, j1 = 2*m + 1;
      int p0 = (j0 & 3) + ((j0 >> 2) << 3) + (hi << 2);
      int p1 = (j1 & 3) + ((j1 >> 2) << 3) + (hi << 2);
      r1m[m] = ((__float_as_uint(r1[p0 << 5]) >> 31) << 15) |
               ((__float_as_uint(r1[p1 << 5]) >> 31) << 31);
      r2m[m] = ((__float_as_uint(r2[p0 << 5]) >> 31) << 15) |
               ((__float_as_uint(r2[p1 << 5]) >> 31) << 31);
    }
  }

  // ---- perm indices, loaded once (coalesced int4) ----
  int pidx[16];
#pragma unroll
  for (int g = 0; g < 4; g++) {
    int4 pi = *(const int4*)(perm + (g << 10) + (tid << 2));
    pidx[4*g+0]=pi.x; pidx[4*g+1]=pi.y; pidx[4*g+2]=pi.z; pidx[4*g+3]=pi.w;
  }

  // ---- x prologue: row 0, wave-coalesced scalars x[32k+q] ----
  const float* xb = x + row0 * 1024 + q;
  float xr[16];
#pragma unroll
  for (int t = 0; t < 2; t++)
#pragma unroll
    for (int m = 0; m < 4; m++) {
      int k0 = 16*t + 8*hi + 2*m;
      xr[(4*t+m)*2 + 0] = xb[k0 << 5];
      xr[(4*t+m)*2 + 1] = xb[(k0 + 1) << 5];
    }

  for (int i = 0; i < RPB; i++) {
    // first A = (x .* rad0)^T : pack then XOR sign
    f16x8 A0, A1;
    {
      H8U4 a0, a1;
#pragma unroll
      for (int t = 0; t < 2; t++)
#pragma unroll
        for (int m = 0; m < 4; m++) {
          int idx = 4*t + m;
          unsigned wd = pkrtz(xr[2*idx], xr[2*idx+1]) ^ r0m[idx];
          if (t == 0) a0.u[m] = wd; else a1.u[m] = wd;
        }
      A0 = a0.h; A1 = a1.h;
    }
    // prefetch next row's x (hides under the MFMA chain)
    if (i + 1 < RPB) {
      const float* xn = xb + (size_t)(i + 1) * 1024;
#pragma unroll
      for (int t = 0; t < 2; t++)
#pragma unroll
        for (int m = 0; m < 4; m++) {
          int k0 = 16*t + 8*hi + 2*m;
          xr[(4*t+m)*2 + 0] = xn[k0 << 5];
          xr[(4*t+m)*2 + 1] = xn[(k0 + 1) << 5];
        }
    }

    f32x16 c;
    c = prod(A0, A1, B0, B1);            // P1
    convA<false>(c, r0m, A0, A1);
    c = prod(A0, A1, B0, B1);            // P2 = fwht1
    convA<true>(c, r1m, A0, A1);
    c = prod(A0, A1, Bs0, Bs1);          // P3 (carries 1/32)
    convA<false>(c, r0m, A0, A1);
    c = prod(A0, A1, B0, B1);            // P4 = fwht2/32
    convA<true>(c, r2m, A0, A1);
    c = prod(A0, A1, Bs0, Bs1);          // P5 (carries 1/32)
    convA<false>(c, r0m, A0, A1);
    c = prod(A0, A1, B0, B1);            // P6 = h : c[j] = h[32*p(j)+q]

    // h -> LDS buf[i&1] at true index (bank = q, 2-way = free)
    float* buf = lds + ((i & 1) << 12);
#pragma unroll
    for (int j = 0; j < 16; j++) {
      int p = (j & 3) + ((j >> 2) << 3) + (hi << 2);
      buf[(w << 10) + (p << 5) + q] = c[j];
    }
    __syncthreads();   // the ONLY barrier per row (double-buffer covers reuse)

    // gather: coalesced 1KB/wave float4 stores
    float* orow = out + (row0 + i) * 4096;
#pragma unroll
    for (int g = 0; g < 4; g++) {
      float4 o;
      o.x = buf[pidx[4*g+0]];
      o.y = buf[pidx[4*g+1]];
      o.z = buf[pidx[4*g+2]];
      o.w = buf[pidx[4*g+3]];
      *(float4*)(orow + (g << 10) + (tid << 2)) = o;
    }
  }
}

extern "C" void kernel_launch(void* const* d_in, const int* in_sizes, int n_in,
                              void* d_out, int out_size, void* d_ws, size_t ws_size,
                              hipStream_t stream) {
  (void)n_in; (void)d_ws; (void)ws_size; (void)out_size;
  const float* x    = (const float*)d_in[0];
  const float* rad  = (const float*)d_in[1];
  const int*   perm = (const int*)d_in[2];
  float*       out  = (float*)d_out;
  const int rows = in_sizes[0] / 1024;  // 16384
  srht_kernel<<<rows / RPB, 256, 0, stream>>>(x, rad, perm, out);
}